// Round 2
// baseline (5835.616 us; speedup 1.0000x reference)
//
#include <hip/hip_runtime.h>

#define BB 16
#define NN 2048
#define FIN 6
#define MTOT (BB*NN)   // 32768

typedef unsigned short u16;  // bf16 storage

// ---- storage-type converters ------------------------------------------------
__device__ inline float ldf(const float* p) { return *p; }
__device__ inline float ldf(const u16* p) {
  unsigned u = ((unsigned)*p) << 16; float f; __builtin_memcpy(&f, &u, 4); return f;
}
__device__ inline void stf(float* p, float v) { *p = v; }
__device__ inline void stf(u16* p, float v) {
  unsigned u; __builtin_memcpy(&u, &v, 4);
  u = (u + 0x7FFFu + ((u >> 16) & 1u)) >> 16;   // RNE
  *p = (u16)u;
}
__device__ inline void ld4(const float* p, float* d) {
  const float4 v = *(const float4*)p; d[0] = v.x; d[1] = v.y; d[2] = v.z; d[3] = v.w;
}
__device__ inline void ld4(const u16* p, float* d) {
  const ushort4 v = *(const ushort4*)p;
  unsigned a = ((unsigned)v.x) << 16, b = ((unsigned)v.y) << 16,
           c = ((unsigned)v.z) << 16, e = ((unsigned)v.w) << 16;
  __builtin_memcpy(&d[0], &a, 4); __builtin_memcpy(&d[1], &b, 4);
  __builtin_memcpy(&d[2], &c, 4); __builtin_memcpy(&d[3], &e, 4);
}
__device__ inline void st4(float* p, const float* v) {
  float4 o; o.x = v[0]; o.y = v[1]; o.z = v[2]; o.w = v[3]; *(float4*)p = o;
}
__device__ inline void st4(u16* p, const float* v) {
  ushort4 o; u16 t[4];
#pragma unroll
  for (int i = 0; i < 4; ++i) { stf(&t[i], v[i]); }
  o.x = t[0]; o.y = t[1]; o.z = t[2]; o.w = t[3];
  *(ushort4*)p = o;
}

// ---------------------------------------------------------------------------
// dinv[b,i] = 1/sqrt( sum_j exp(-||x_i - x_j||^2) )
// ---------------------------------------------------------------------------
__global__ __launch_bounds__(256) void k_dinv(const float* __restrict__ x,
                                              float* __restrict__ dinv) {
  __shared__ float xs[NN][FIN];
  __shared__ float sqs[NN];
  const int b = blockIdx.y;
  const float* xb = x + (size_t)b * NN * FIN;
  for (int l = threadIdx.x; l < NN * FIN; l += 256) ((float*)xs)[l] = xb[l];
  __syncthreads();
  for (int j = threadIdx.x; j < NN; j += 256) {
    float s = 0.f;
#pragma unroll
    for (int f = 0; f < FIN; ++f) { float v = xs[j][f]; s = fmaf(v, v, s); }
    sqs[j] = s;
  }
  __syncthreads();
  const int i = blockIdx.x * 256 + threadIdx.x;
  float xi[FIN];
#pragma unroll
  for (int f = 0; f < FIN; ++f) xi[f] = xs[i][f];
  const float sqi = sqs[i];
  float acc0 = 0.f, acc1 = 0.f, acc2 = 0.f, acc3 = 0.f;
  for (int j = 0; j < NN; j += 4) {
#pragma unroll
    for (int u = 0; u < 4; ++u) {
      const int jj = j + u;
      float dot = 0.f;
#pragma unroll
      for (int f = 0; f < FIN; ++f) dot = fmaf(xs[jj][f], xi[f], dot);
      const float e = __expf(2.f * dot - sqi - sqs[jj]);
      if (u == 0) acc0 += e; else if (u == 1) acc1 += e;
      else if (u == 2) acc2 += e; else acc3 += e;
    }
  }
  dinv[b * NN + i] = 1.0f / sqrtf((acc0 + acc1) + (acc2 + acc3));
}

// ---------------------------------------------------------------------------
// L[b,i,j] = (i==j) - exp(-d2_ij) * dinv_i * dinv_j   (stored as ST)
// ---------------------------------------------------------------------------
template <typename ST>
__global__ __launch_bounds__(256) void k_lap(const float* __restrict__ x,
                                             const float* __restrict__ dinv,
                                             ST* __restrict__ Lm) {
  const int b = blockIdx.z;
  const int i0 = blockIdx.y * 32;
  const int j0 = blockIdx.x * 256;
  __shared__ float xi[32][FIN];
  __shared__ float di[32];
  const int t = threadIdx.x;
  const float* xb = x + (size_t)b * NN * FIN;
  if (t < 32 * FIN) ((float*)xi)[t] = xb[i0 * FIN + t];
  if (t >= 224) di[t - 224] = dinv[b * NN + i0 + (t - 224)];
  const int j = j0 + t;
  float xj[FIN];
#pragma unroll
  for (int f = 0; f < FIN; ++f) xj[f] = xb[j * FIN + f];
  float sqj = 0.f;
#pragma unroll
  for (int f = 0; f < FIN; ++f) sqj = fmaf(xj[f], xj[f], sqj);
  const float dj = dinv[b * NN + j];
  __syncthreads();
  ST* Lb = Lm + (size_t)b * NN * NN;
#pragma unroll 4
  for (int ii = 0; ii < 32; ++ii) {
    float sqi = 0.f, dot = 0.f;
#pragma unroll
    for (int f = 0; f < FIN; ++f) {
      const float v = xi[ii][f];
      sqi = fmaf(v, v, sqi);
      dot = fmaf(v, xj[f], dot);
    }
    float val = -__expf(2.f * dot - sqi - sqj) * di[ii] * dj;
    if (i0 + ii == j) val += 1.f;
    stf(&Lb[(size_t)(i0 + ii) * NN + j], val);
  }
}

// ---------------------------------------------------------------------------
// T1 slot0 [M,22] = [x[m,0:6], one_hot(cat[b],16)]
// ---------------------------------------------------------------------------
template <typename ST>
__global__ void k_h0(const float* __restrict__ x, const int* __restrict__ cat,
                     ST* __restrict__ T1) {
  const int idx = blockIdx.x * 256 + threadIdx.x;
  if (idx >= MTOT * 22) return;
  const int m = idx / 22, c = idx % 22;
  const int b = m / NN;
  float v;
  if (c < 6) v = x[(size_t)m * 6 + c];
  else v = (cat[b] == (c - 6)) ? 1.f : 0.f;
  stf(&T1[(size_t)m * 22 + c], v);
}

// ---------------------------------------------------------------------------
// Cheb step:  Out = alpha * (L[b] @ In) + beta * Prev   (slot buffers [M,F])
// grid: (F_tiles, NN/64, BB); 256 thr; 64x64 tile, Kc=32, 4x4 micro
// ---------------------------------------------------------------------------
template <typename ST>
__global__ __launch_bounds__(256) void k_cheb(const ST* __restrict__ Lm,
                                              const ST* __restrict__ In,
                                              const ST* __restrict__ Prev,
                                              ST* __restrict__ Out,
                                              int F, float alpha, float beta) {
  const int b = blockIdx.z;
  const int f0 = blockIdx.x * 64;
  const int i0 = blockIdx.y * 64;
  const size_t r0 = (size_t)b * NN;
  const ST* Lb = Lm + (size_t)b * NN * NN;
  __shared__ float As[32][68];
  __shared__ float Bs[32][68];
  const int tid = threadIdx.x;
  const int ty = tid >> 4, tx = tid & 15;
  const bool vecF = ((F & 63) == 0);
  float acc[4][4] = {};
  for (int k0 = 0; k0 < NN; k0 += 32) {
#pragma unroll
    for (int h = 0; h < 2; ++h) {
      const int l = tid + h * 256;
      const int row = l >> 3, q = l & 7;
      float a4[4];
      ld4(&Lb[(size_t)(i0 + row) * NN + k0 + q * 4], a4);
      As[q * 4 + 0][row] = a4[0]; As[q * 4 + 1][row] = a4[1];
      As[q * 4 + 2][row] = a4[2]; As[q * 4 + 3][row] = a4[3];
    }
#pragma unroll
    for (int h = 0; h < 2; ++h) {
      const int l = tid + h * 256;
      const int kr = l >> 4, fq = (l & 15) * 4;
      const ST* src = In + (r0 + k0 + kr) * (size_t)F + f0 + fq;
      if (vecF) {
        ld4(src, &Bs[kr][fq]);
      } else {
#pragma unroll
        for (int c = 0; c < 4; ++c)
          Bs[kr][fq + c] = (f0 + fq + c < F) ? ldf(&src[c]) : 0.f;
      }
    }
    __syncthreads();
#pragma unroll
    for (int k = 0; k < 32; ++k) {
      const float4 a4 = *(const float4*)(&As[k][ty * 4]);
      const float4 b4 = *(const float4*)(&Bs[k][tx * 4]);
      const float a[4] = {a4.x, a4.y, a4.z, a4.w};
      const float bb[4] = {b4.x, b4.y, b4.z, b4.w};
#pragma unroll
      for (int r = 0; r < 4; ++r)
#pragma unroll
        for (int c = 0; c < 4; ++c) acc[r][c] = fmaf(a[r], bb[c], acc[r][c]);
    }
    __syncthreads();
  }
#pragma unroll
  for (int r = 0; r < 4; ++r) {
    const size_t gm = r0 + i0 + ty * 4 + r;
    const int f = f0 + tx * 4;
    float v[4];
#pragma unroll
    for (int c = 0; c < 4; ++c) {
      v[c] = alpha * acc[r][c];
      if (beta != 0.f && f + c < F) v[c] = fmaf(beta, ldf(&Prev[gm * F + f + c]), v[c]);
    }
    if (vecF) {
      st4(&Out[gm * F + f], v);
    } else {
#pragma unroll
      for (int c = 0; c < 4; ++c)
        if (f + c < F) stf(&Out[gm * F + f + c], v[c]);
    }
  }
}

// ---------------------------------------------------------------------------
// C[M,Fout] = relu(A @ W + bias + br)
// A is slot-major: element (m,kk) at slotbase + m*Fin + (kk%Fin), slot = kk/Fin.
// sstride>0: slotbase = A0 + slot*sstride. sstride==0: slot in {0,1,2} -> A0/A1/A2.
// finShift>0: Fin is 2^finShift (fast slot calc). grid: (ceil(Fout/64), MTOT/64)
// ---------------------------------------------------------------------------
template <typename ST, typename CT>
__global__ __launch_bounds__(256) void k_gemm(const ST* __restrict__ A0,
                                              const ST* __restrict__ A1,
                                              const ST* __restrict__ A2,
                                              size_t sstride, int Fin, int finShift, int K,
                                              const float* __restrict__ W, int Fout,
                                              const float* __restrict__ bias,
                                              const float* __restrict__ br,
                                              CT* __restrict__ C) {
  const int f0 = blockIdx.x * 64;
  const int m0 = blockIdx.y * 64;
  __shared__ float As[32][68];
  __shared__ float Bs[32][68];
  const int tid = threadIdx.x;
  const int ty = tid >> 4, tx = tid & 15;
  const bool avec = ((Fin & 31) == 0);
  const bool wvec = ((Fout & 3) == 0);
  float acc[4][4] = {};
  const int nk = (K + 31) & ~31;
  for (int k0 = 0; k0 < nk; k0 += 32) {
    // A tile: rows m0..m0+63, k-cols k0..k0+31
#pragma unroll
    for (int h = 0; h < 2; ++h) {
      const int l = tid + h * 256;
      const int row = l >> 3, q = l & 7;
      const int kk = k0 + q * 4;
      const size_t m = (size_t)(m0 + row);
      if (avec && kk + 3 < K) {
        const int slot = kk >> finShift;
        const int fin = kk & (Fin - 1);
        const ST* base = sstride ? A0 + (size_t)slot * sstride
                                 : (slot == 0 ? A0 : slot == 1 ? A1 : A2);
        float a4[4];
        ld4(&base[m * (size_t)Fin + fin], a4);
        As[q * 4 + 0][row] = a4[0]; As[q * 4 + 1][row] = a4[1];
        As[q * 4 + 2][row] = a4[2]; As[q * 4 + 3][row] = a4[3];
      } else {
#pragma unroll
        for (int c = 0; c < 4; ++c) {
          const int k = kk + c;
          float v = 0.f;
          if (k < K) {
            int slot, fin;
            if (finShift) { slot = k >> finShift; fin = k & (Fin - 1); }
            else { slot = k / Fin; fin = k - slot * Fin; }
            const ST* base = sstride ? A0 + (size_t)slot * sstride
                                     : (slot == 0 ? A0 : slot == 1 ? A1 : A2);
            v = ldf(&base[m * (size_t)Fin + fin]);
          }
          As[q * 4 + c][row] = v;
        }
      }
    }
    // W tile
#pragma unroll
    for (int h = 0; h < 2; ++h) {
      const int l = tid + h * 256;
      const int kr = l >> 4, fq = (l & 15) * 4;
      const int kk = k0 + kr, fg = f0 + fq;
      float bv[4] = {0.f, 0.f, 0.f, 0.f};
      if (kk < K) {
        const float* src = &W[(size_t)kk * Fout + fg];
        if (wvec && fg + 3 < Fout) { ld4(src, bv); }
        else {
#pragma unroll
          for (int c = 0; c < 4; ++c) if (fg + c < Fout) bv[c] = src[c];
        }
      }
      Bs[kr][fq + 0] = bv[0]; Bs[kr][fq + 1] = bv[1];
      Bs[kr][fq + 2] = bv[2]; Bs[kr][fq + 3] = bv[3];
    }
    __syncthreads();
#pragma unroll
    for (int k = 0; k < 32; ++k) {
      const float4 a4 = *(const float4*)(&As[k][ty * 4]);
      const float4 b4 = *(const float4*)(&Bs[k][tx * 4]);
      const float a[4] = {a4.x, a4.y, a4.z, a4.w};
      const float bb[4] = {b4.x, b4.y, b4.z, b4.w};
#pragma unroll
      for (int r = 0; r < 4; ++r)
#pragma unroll
        for (int c = 0; c < 4; ++c) acc[r][c] = fmaf(a[r], bb[c], acc[r][c]);
    }
    __syncthreads();
  }
  float bb[4];
#pragma unroll
  for (int c = 0; c < 4; ++c) {
    const int f = f0 + tx * 4 + c;
    bb[c] = (f < Fout) ? (bias[f] + br[f]) : 0.f;
  }
#pragma unroll
  for (int r = 0; r < 4; ++r) {
    const size_t m = (size_t)(m0 + ty * 4 + r);
    const int f = f0 + tx * 4;
    float v[4];
#pragma unroll
    for (int c = 0; c < 4; ++c) v[c] = fmaxf(acc[r][c] + bb[c], 0.f);
    if (wvec && f + 3 < Fout) {
      st4(&C[m * (size_t)Fout + f], v);
    } else {
#pragma unroll
      for (int c = 0; c < 4; ++c)
        if (f + c < Fout) stf(&C[m * (size_t)Fout + f + c], v[c]);
    }
  }
}

// ---------------------------------------------------------------------------
template <typename ST>
static void run_plan(void* const* d_in, void* d_out, void* d_ws, hipStream_t stream) {
  const float* x    = (const float*)d_in[0];
  const int*   cat  = (const int*)  d_in[1];
  const float* W1   = (const float*)d_in[2];
  const float* b1   = (const float*)d_in[3];
  const float* W2   = (const float*)d_in[4];
  const float* b2   = (const float*)d_in[5];
  const float* W3   = (const float*)d_in[6];
  const float* b3   = (const float*)d_in[7];
  const float* fc1w = (const float*)d_in[8];
  const float* fc1b = (const float*)d_in[9];
  const float* fc2w = (const float*)d_in[10];
  const float* fc2b = (const float*)d_in[11];
  const float* fc3w = (const float*)d_in[12];
  const float* fc3b = (const float*)d_in[13];
  const float* br0  = (const float*)d_in[14];
  const float* br1  = (const float*)d_in[15];
  const float* br2  = (const float*)d_in[16];
  const float* br3  = (const float*)d_in[17];
  const float* br4  = (const float*)d_in[18];
  const float* br5  = (const float*)d_in[19];

  // Region layout (ST elements). Lifetimes allow the overlays shown.
  const size_t SL  = (size_t)BB * NN * NN;       // 67,108,864  L / later h3 [M,1024]
  const size_t S5  = (size_t)MTOT * 512;         // 16,777,216
  ST* Lp  = (ST*)d_ws;
  ST* RA  = Lp + SL;          // T1 (6x[M,22]) -> T3b [M,512] -> hcatA [M,512]
  ST* RB  = RA + S5;          // T3a [M,512]           (== RA + M*512: fc2 stride)
  ST* RC  = RB + S5;          // T2 (5x[M,128]) -> T3c [M,512] -> h5 [M,128]
  float* dinv = (float*)(RC + (size_t)MTOT * 640);
  ST* T1 = RA; ST* T3b = RA; ST* hcatA = RA;
  ST* T3a = RB;
  ST* T2 = RC; ST* T3c = RC; ST* h5 = RC;
  ST* h3 = Lp;

  // Laplacian
  k_dinv<<<dim3(NN / 256, BB), 256, 0, stream>>>(x, dinv);
  k_lap<ST><<<dim3(NN / 256, NN / 32, BB), 256, 0, stream>>>(x, dinv, Lp);

  // layer 1 (K=6, Fin=22, Fout=128)
  k_h0<ST><<<dim3((MTOT * 22 + 255) / 256), 256, 0, stream>>>(x, cat, T1);
  const size_t s1 = (size_t)MTOT * 22;
  k_cheb<ST><<<dim3(1, NN / 64, BB), 256, 0, stream>>>(Lp, T1, T1, T1 + s1, 22, 1.f, 0.f);
  for (int k = 2; k < 6; ++k)
    k_cheb<ST><<<dim3(1, NN / 64, BB), 256, 0, stream>>>(
        Lp, T1 + (k - 1) * s1, T1 + (k - 2) * s1, T1 + k * s1, 22, 2.f, -1.f);
  k_gemm<ST, ST><<<dim3(2, MTOT / 64), 256, 0, stream>>>(
      T1, T1, T1, s1, 22, 0, 132, W1, 128, b1, br0, T2);

  // layer 2 (K=5, Fin=128, Fout=512)
  const size_t s2 = (size_t)MTOT * 128;
  k_cheb<ST><<<dim3(2, NN / 64, BB), 256, 0, stream>>>(Lp, T2, T2, T2 + s2, 128, 1.f, 0.f);
  for (int k = 2; k < 5; ++k)
    k_cheb<ST><<<dim3(2, NN / 64, BB), 256, 0, stream>>>(
        Lp, T2 + (k - 1) * s2, T2 + (k - 2) * s2, T2 + k * s2, 128, 2.f, -1.f);
  k_gemm<ST, ST><<<dim3(8, MTOT / 64), 256, 0, stream>>>(
      T2, T2, T2, s2, 128, 7, 640, W2, 512, b2, br1, T3a);

  // layer 3 (K=3, Fin=512, Fout=1024); slots: T3a(RB), T3b(RA), T3c(RC)
  k_cheb<ST><<<dim3(8, NN / 64, BB), 256, 0, stream>>>(Lp, T3a, T3a, T3b, 512, 1.f, 0.f);
  k_cheb<ST><<<dim3(8, NN / 64, BB), 256, 0, stream>>>(Lp, T3b, T3a, T3c, 512, 2.f, -1.f);
  k_gemm<ST, ST><<<dim3(16, MTOT / 64), 256, 0, stream>>>(
      T3a, T3b, T3c, 0, 512, 9, 1536, W3, 1024, b3, br2, h3);   // h3 overlays dead L

  // fc head
  k_gemm<ST, ST><<<dim3(8, MTOT / 64), 256, 0, stream>>>(
      h3, h3, h3, (size_t)MTOT * 1024, 1024, 10, 1024, fc1w, 512, fc1b, br3, hcatA);
  // fc2: A = [hcatA | T3a], uniform stride M*512 (RB == RA + M*512)
  k_gemm<ST, ST><<<dim3(2, MTOT / 64), 256, 0, stream>>>(
      hcatA, hcatA, hcatA, S5, 512, 9, 1024, fc2w, 128, fc2b, br4, h5);
  k_gemm<ST, float><<<dim3(1, MTOT / 64), 256, 0, stream>>>(
      h5, h5, h5, (size_t)MTOT * 128, 128, 7, 128, fc3w, 50, fc3b, br5, (float*)d_out);
}

extern "C" void kernel_launch(void* const* d_in, const int* in_sizes, int n_in,
                              void* d_out, int out_size, void* d_ws, size_t ws_size,
                              hipStream_t stream) {
  // total ST elements: L(67,108,864) + RA(16,777,216) + RB(16,777,216) + RC(20,971,520)
  const size_t elems = 121634816ull;
  const size_t need32 = elems * 4 + 131072;   // ~486.7 MB, fp32 plan
  const size_t need16 = elems * 2 + 131072;   // ~243.4 MB (232.1 MiB), bf16 plan
  if (ws_size >= need32) {
    run_plan<float>(d_in, d_out, d_ws, stream);
  } else if (ws_size >= need16) {
    run_plan<u16>(d_in, d_out, d_ws, stream);
  }
  // else: insufficient scratch -> fail loudly (output stays zero)
}

// Round 5
// 2411.835 us; speedup vs baseline: 2.4196x; 2.4196x over previous
//
#include <hip/hip_runtime.h>

#define BB 16
#define NN 2048
#define FIN 6
#define MTOT (BB*NN)   // 32768

typedef unsigned short u16;
typedef __attribute__((ext_vector_type(8))) short  short8;
typedef __attribute__((ext_vector_type(8))) unsigned short ush8;
typedef __attribute__((ext_vector_type(4))) float  f32x4;

// ---- bf16 helpers ----------------------------------------------------------
__device__ inline float ldf(const u16* p) {
  unsigned u = ((unsigned)*p) << 16; float f; __builtin_memcpy(&f, &u, 4); return f;
}
__device__ inline u16 tobf(float v) {
  unsigned u; __builtin_memcpy(&u, &v, 4);
  u = (u + 0x7FFFu + ((u >> 16) & 1u)) >> 16;   // RNE
  return (u16)u;
}
__device__ inline void stf(u16* p, float v) { *p = tobf(v); }

// ---------------------------------------------------------------------------
// dinv[b,i] = 1/sqrt( sum_j exp(-||x_i-x_j||^2) )
// ---------------------------------------------------------------------------
__global__ __launch_bounds__(256) void k_dinv(const float* __restrict__ x,
                                              float* __restrict__ dinv) {
  __shared__ float xs[NN][FIN];
  __shared__ float sqs[NN];
  const int b = blockIdx.y;
  const float* xb = x + (size_t)b * NN * FIN;
  for (int l = threadIdx.x; l < NN * FIN; l += 256) ((float*)xs)[l] = xb[l];
  __syncthreads();
  for (int j = threadIdx.x; j < NN; j += 256) {
    float s = 0.f;
#pragma unroll
    for (int f = 0; f < FIN; ++f) { float v = xs[j][f]; s = fmaf(v, v, s); }
    sqs[j] = s;
  }
  __syncthreads();
  const int i = blockIdx.x * 256 + threadIdx.x;
  float xi[FIN];
#pragma unroll
  for (int f = 0; f < FIN; ++f) xi[f] = xs[i][f];
  const float sqi = sqs[i];
  float a0 = 0.f, a1 = 0.f, a2 = 0.f, a3 = 0.f;
  for (int j = 0; j < NN; j += 4) {
#pragma unroll
    for (int u = 0; u < 4; ++u) {
      const int jj = j + u;
      float dot = 0.f;
#pragma unroll
      for (int f = 0; f < FIN; ++f) dot = fmaf(xs[jj][f], xi[f], dot);
      const float e = __expf(2.f * dot - sqi - sqs[jj]);
      if (u == 0) a0 += e; else if (u == 1) a1 += e; else if (u == 2) a2 += e; else a3 += e;
    }
  }
  dinv[b * NN + i] = 1.0f / sqrtf((a0 + a1) + (a2 + a3));
}

// ---------------------------------------------------------------------------
// L[b,i,j] = (i==j) - exp(-d2_ij)*dinv_i*dinv_j   (bf16)
// ---------------------------------------------------------------------------
__global__ __launch_bounds__(256) void k_lap(const float* __restrict__ x,
                                             const float* __restrict__ dinv,
                                             u16* __restrict__ Lm) {
  const int b = blockIdx.z;
  const int i0 = blockIdx.y * 32;
  const int j0 = blockIdx.x * 256;
  __shared__ float xi[32][FIN];
  __shared__ float di[32];
  const int t = threadIdx.x;
  const float* xb = x + (size_t)b * NN * FIN;
  if (t < 32 * FIN) ((float*)xi)[t] = xb[i0 * FIN + t];
  if (t >= 224) di[t - 224] = dinv[b * NN + i0 + (t - 224)];
  const int j = j0 + t;
  float xj[FIN];
#pragma unroll
  for (int f = 0; f < FIN; ++f) xj[f] = xb[j * FIN + f];
  float sqj = 0.f;
#pragma unroll
  for (int f = 0; f < FIN; ++f) sqj = fmaf(xj[f], xj[f], sqj);
  const float dj = dinv[b * NN + j];
  __syncthreads();
  u16* Lb = Lm + (size_t)b * NN * NN;
#pragma unroll 4
  for (int ii = 0; ii < 32; ++ii) {
    float sqi = 0.f, dot = 0.f;
#pragma unroll
    for (int f = 0; f < FIN; ++f) {
      const float v = xi[ii][f];
      sqi = fmaf(v, v, sqi);
      dot = fmaf(v, xj[f], dot);
    }
    float val = -__expf(2.f * dot - sqi - sqj) * di[ii] * dj;
    if (i0 + ii == j) val += 1.f;
    stf(&Lb[(size_t)(i0 + ii) * NN + j], val);
  }
}

// ---------------------------------------------------------------------------
// T1T rows [22][Mtot]: row c, col m
// ---------------------------------------------------------------------------
__global__ void k_h0T(const float* __restrict__ x, const int* __restrict__ cat,
                      u16* __restrict__ T1T) {
  const int c = blockIdx.y;
  const int m = blockIdx.x * 256 + threadIdx.x;
  float v;
  if (c < 6) v = x[(size_t)m * 6 + c];
  else v = (cat[m >> 11] == (c - 6)) ? 1.f : 0.f;
  stf(&T1T[(size_t)c * MTOT + m], v);
}

// ---------------------------------------------------------------------------
// weight transpose: in fp32 [R][C] -> out bf16 [C][R]
// ---------------------------------------------------------------------------
__global__ void k_wt(const float* __restrict__ in, u16* __restrict__ out, int R, int C) {
  const int r = blockIdx.x * 256 + threadIdx.x;
  const int c = blockIdx.y;
  if (r < R) stf(&out[(size_t)c * R + r], in[(size_t)r * C + c]);
}

// ---------------------------------------------------------------------------
// activation transpose: in bf16 [F][Mt] -> out bf16 [Mt][F]
// ---------------------------------------------------------------------------
__global__ __launch_bounds__(256) void k_actT(const u16* __restrict__ in,
                                              u16* __restrict__ out, int F) {
  __shared__ u16 t[64][70];
  const int m0 = blockIdx.x * 64;
  const int f0 = blockIdx.y * 64;
  const int tid = threadIdx.x;
#pragma unroll
  for (int v = 0; v < 4; ++v) {
    const int flat = v * 256 + tid;
    const int fr = flat >> 4;
    const int mq = (flat & 15) * 4;
    ushort4 val = {0, 0, 0, 0};
    if (f0 + fr < F) val = *(const ushort4*)&in[(size_t)(f0 + fr) * MTOT + m0 + mq];
    t[fr][mq + 0] = val.x; t[fr][mq + 1] = val.y;
    t[fr][mq + 2] = val.z; t[fr][mq + 3] = val.w;
  }
  __syncthreads();
#pragma unroll
  for (int v = 0; v < 4; ++v) {
    const int flat = v * 256 + tid;
    const int mr = flat >> 4;
    const int fq = (flat & 15) * 4;
    if (f0 + fq >= F) continue;
    u16* dst = &out[(size_t)(m0 + mr) * F + f0 + fq];
    if (f0 + fq + 3 < F) {
      ushort4 o;
      o.x = t[fq + 0][mr]; o.y = t[fq + 1][mr];
      o.z = t[fq + 2][mr]; o.w = t[fq + 3][mr];
      *(ushort4*)dst = o;
    } else {
#pragma unroll
      for (int e = 0; e < 4; ++e)
        if (f0 + fq + e < F) dst[e] = t[fq + e][mr];
    }
  }
}

// ---------------------------------------------------------------------------
// stage R x 64 bf16 tile (rows of operand, k-fast) into swizzled LDS
// ---------------------------------------------------------------------------
template <int R>
__device__ inline void stage(u16* __restrict__ s,
                             const u16* __restrict__ p0, long ld0,
                             const u16* __restrict__ p1, long ld1, int ksplit,
                             int rbase, int rowN, int k0, int K, int tid) {
#pragma unroll
  for (int v = 0; v < R / 32; ++v) {
    const int flat = v * 256 + tid;
    const int r = flat >> 3;
    const int ks = (flat & 7) * 8;
    const int gr = rbase + r;
    const int gk = k0 + ks;
    ush8 tmp;
    if (gr < rowN) {
      const u16* p = nullptr; long ld = 0; int col = 0;
      if (gk + 8 <= ksplit) { p = p0; ld = ld0; col = gk; }
      else if (gk >= ksplit) { p = p1; ld = ld1; col = gk - ksplit; }
      if (p && gk + 8 <= K) {
        const u16* a = p + (size_t)gr * ld + col;
        if (((uintptr_t)a & 15) == 0) {
          tmp = *(const ush8*)a;
        } else {
#pragma unroll
          for (int e = 0; e < 8; ++e) tmp[e] = a[e];
        }
      } else {
#pragma unroll
        for (int e = 0; e < 8; ++e) {
          const int kk = gk + e;
          u16 val = 0;
          if (kk < K) {
            if (kk < ksplit) val = p0[(size_t)gr * ld0 + kk];
            else val = p1[(size_t)gr * ld1 + (kk - ksplit)];
          }
          tmp[e] = val;
        }
      }
    } else {
#pragma unroll
      for (int e = 0; e < 8; ++e) tmp[e] = 0;
    }
    const int c = ks ^ ((r & 7) << 3);
    *(ush8*)&s[r * 64 + c] = tmp;
  }
}

// ---------------------------------------------------------------------------
// MFMA GEMM: D[i][j] = sum_k P[i][k] * Q[j][k]   (both operands k-fast rows)
// store: Out[jj*ldo + ii]  ([j][i-fast], matches mfma C layout)
// EPI 0: v = alpha*acc + beta*Prev[jj*ldo+ii]        (cheb)
// EPI 1: v = relu(acc + bias[idx] + br[idx])         (idx = i if biasOnI else j)
// ---------------------------------------------------------------------------
template <int BM, int BN, int EPI, typename OT>
__global__ __launch_bounds__(256) void k_mm(
    const u16* __restrict__ P, long ldp, int rowsP, long strideP,
    const u16* __restrict__ Q0, long ldq0,
    const u16* __restrict__ Q1, long ldq1, int ksplit,
    int rowsQ, long strideQ,
    int K,
    OT* __restrict__ Out, long ldo, long strideO,
    const u16* __restrict__ Prev, float alpha, float beta,
    const float* __restrict__ bias, const float* __restrict__ br, int biasOnI) {
  const int b = blockIdx.z;
  const int i0 = blockIdx.y * BM;
  const int j0 = blockIdx.x * BN;
  const u16* Pb = P + (size_t)b * strideP;
  const u16* Qb0 = Q0 + (size_t)b * strideQ;
  const u16* Qb1 = Q1 ? Q1 + (size_t)b * strideQ : nullptr;
  OT* Ob = Out + (size_t)b * strideO;
  const u16* Vb = Prev ? Prev + (size_t)b * strideO : nullptr;

  __shared__ u16 Ps[BM * 64];
  __shared__ u16 Qs[BN * 64];
  const int tid = threadIdx.x;
  const int lane = tid & 63;
  const int w = tid >> 6;
  const int wr = w >> 1, wc = w & 1;
  constexpr int FI = BM / 32;
  constexpr int FJ = BN / 32;
  f32x4 acc[FI][FJ];
#pragma unroll
  for (int i = 0; i < FI; ++i)
#pragma unroll
    for (int j = 0; j < FJ; ++j) acc[i][j] = (f32x4){0.f, 0.f, 0.f, 0.f};

  const int nk = (K + 63) >> 6;
  for (int t = 0; t < nk; ++t) {
    const int k0 = t * 64;
    stage<BM>(Ps, Pb, ldp, nullptr, 0, 0x40000000, i0, rowsP, k0, K, tid);
    stage<BN>(Qs, Qb0, ldq0, Qb1, ldq1, ksplit, j0, rowsQ, k0, K, tid);
    __syncthreads();
#pragma unroll
    for (int h = 0; h < 2; ++h) {
      short8 pf[FI], qf[FJ];
#pragma unroll
      for (int i = 0; i < FI; ++i) {
        const int r = wr * (BM / 2) + i * 16 + (lane & 15);
        const int c = (h * 32 + ((lane >> 4) * 8)) ^ ((r & 7) << 3);
        pf[i] = *(const short8*)&Ps[r * 64 + c];
      }
#pragma unroll
      for (int j = 0; j < FJ; ++j) {
        const int r = wc * (BN / 2) + j * 16 + (lane & 15);
        const int c = (h * 32 + ((lane >> 4) * 8)) ^ ((r & 7) << 3);
        qf[j] = *(const short8*)&Qs[r * 64 + c];
      }
#pragma unroll
      for (int i = 0; i < FI; ++i)
#pragma unroll
        for (int j = 0; j < FJ; ++j)
          acc[i][j] = __builtin_amdgcn_mfma_f32_16x16x32_bf16(pf[i], qf[j], acc[i][j], 0, 0, 0);
    }
    __syncthreads();
  }

  const int ibase = i0 + wr * (BM / 2);
  const int jbase = j0 + wc * (BN / 2);
#pragma unroll
  for (int j = 0; j < FJ; ++j) {
    const int jj = jbase + j * 16 + (lane & 15);
    if (jj >= rowsQ) continue;
    float bj = 0.f;
    if (EPI == 1 && !biasOnI) bj = bias[jj] + br[jj];
#pragma unroll
    for (int i = 0; i < FI; ++i) {
      const int ii = ibase + i * 16 + ((lane >> 4) << 2);
      f32x4 a = acc[i][j];
      float v[4];
#pragma unroll
      for (int e = 0; e < 4; ++e) {
        float xv = a[e];
        if (EPI == 0) {
          xv *= alpha;
          if (beta != 0.f) xv = fmaf(beta, ldf(&Vb[(size_t)jj * ldo + ii + e]), xv);
        } else {
          float bb = bj;
          if (biasOnI) bb = (ii + e < rowsP) ? (bias[ii + e] + br[ii + e]) : 0.f;
          xv = fmaxf(xv + bb, 0.f);
        }
        v[e] = xv;
      }
      if constexpr (sizeof(OT) == 2) {
        u16* dst = (u16*)&Ob[(size_t)jj * ldo + ii];
        if (ii + 3 < rowsP) {
          ushort4 o; o.x = tobf(v[0]); o.y = tobf(v[1]); o.z = tobf(v[2]); o.w = tobf(v[3]);
          *(ushort4*)dst = o;
        } else {
#pragma unroll
          for (int e = 0; e < 4; ++e) if (ii + e < rowsP) dst[e] = tobf(v[e]);
        }
      } else {
        float* dst = (float*)&Ob[(size_t)jj * ldo + ii];
#pragma unroll
        for (int e = 0; e < 4; ++e) if (ii + e < rowsP) dst[e] = v[e];
      }
    }
  }
}

// ---------------------------------------------------------------------------
extern "C" void kernel_launch(void* const* d_in, const int* in_sizes, int n_in,
                              void* d_out, int out_size, void* d_ws, size_t ws_size,
                              hipStream_t stream) {
  const float* x    = (const float*)d_in[0];
  const int*   cat  = (const int*)  d_in[1];
  const float* W1   = (const float*)d_in[2];
  const float* b1   = (const float*)d_in[3];
  const float* W2   = (const float*)d_in[4];
  const float* b2   = (const float*)d_in[5];
  const float* W3   = (const float*)d_in[6];
  const float* b3   = (const float*)d_in[7];
  const float* fc1w = (const float*)d_in[8];
  const float* fc1b = (const float*)d_in[9];
  const float* fc2w = (const float*)d_in[10];
  const float* fc2b = (const float*)d_in[11];
  const float* fc3w = (const float*)d_in[12];
  const float* fc3b = (const float*)d_in[13];
  const float* br0  = (const float*)d_in[14];
  const float* br1  = (const float*)d_in[15];
  const float* br2  = (const float*)d_in[16];
  const float* br3  = (const float*)d_in[17];
  const float* br4  = (const float*)d_in[18];
  const float* br5  = (const float*)d_in[19];

  if (ws_size < 240170496ull) return;  // fail loudly

  u16* ws = (u16*)d_ws;
  u16* Wt1  = ws;                    // [128][132]
  u16* Wt2  = Wt1 + 16896;           // [512][640]
  u16* Wt3  = Wt2 + 327680;          // [1024][1536]
  u16* Wtf1 = Wt3 + 1572864;         // [512][1024]
  u16* Wtf2 = Wtf1 + 524288;         // [128][1024]
  u16* Wtf3 = Wtf2 + 131072;         // [50][128]
  float* dinv = (float*)(Wtf3 + 6400);
  u16* Lbuf = ws + 2644736;          // [16][2048][2048] -> later L3rm [M][1536]
  u16* ACT  = Lbuf + 67108864;       // 50,331,648 elems

  u16* T1T   = ACT;                  // [132][M]
  u16* L1rm  = ACT + 4325376;        // [M][132]
  u16* T2T   = ACT;                  // [640][M]
  u16* L2rm  = ACT + 20971520;       // [M][640]
  u16* T3T   = ACT;                  // [1536][M]
  u16* L3rm  = Lbuf;                 // [M][1536]
  u16* h3rm  = ACT;                  // [M][1024]
  u16* fc1o  = ACT + 33554432;       // [M][512]
  u16* h5    = ACT;                  // [M][128]

  const long MT = MTOT;
  const int BIG = 0x40000000;

  // weights -> bf16 transposed
  k_wt<<<dim3(1, 128), 256, 0, stream>>>(W1, Wt1, 132, 128);
  k_wt<<<dim3(3, 512), 256, 0, stream>>>(W2, Wt2, 640, 512);
  k_wt<<<dim3(6, 1024), 256, 0, stream>>>(W3, Wt3, 1536, 1024);
  k_wt<<<dim3(4, 512), 256, 0, stream>>>(fc1w, Wtf1, 1024, 512);
  k_wt<<<dim3(4, 128), 256, 0, stream>>>(fc2w, Wtf2, 1024, 128);
  k_wt<<<dim3(1, 50), 256, 0, stream>>>(fc3w, Wtf3, 128, 50);

  // Laplacian (bf16)
  k_dinv<<<dim3(8, BB), 256, 0, stream>>>(x, dinv);
  k_lap<<<dim3(8, 64, BB), 256, 0, stream>>>(x, dinv, Lbuf);

  // ---- layer 1: 6 slots of 22 rows in T1T ----
  k_h0T<<<dim3(128, 22), 256, 0, stream>>>(x, cat, T1T);
  {
    const size_t s = (size_t)22 * MT;
    k_mm<128, 32, 0, u16><<<dim3(1, 16, BB), 256, 0, stream>>>(
        Lbuf, NN, NN, (long)NN * NN, T1T, MT, nullptr, 0, BIG, 22, NN,
        NN, T1T + s, MT, NN, nullptr, 1.f, 0.f, nullptr, nullptr, 0);
    for (int k = 2; k < 6; ++k)
      k_mm<128, 32, 0, u16><<<dim3(1, 16, BB), 256, 0, stream>>>(
          Lbuf, NN, NN, (long)NN * NN, T1T + (k - 1) * s, MT, nullptr, 0, BIG, 22, NN,
          NN, T1T + k * s, MT, NN, T1T + (k - 2) * s, 2.f, -1.f, nullptr, nullptr, 0);
  }
  k_actT<<<dim3(512, 3), 256, 0, stream>>>(T1T, L1rm, 132);
  // combine1 -> T2T slot0 (transposed)
  k_mm<128, 128, 1, u16><<<dim3(1, 256, 1), 256, 0, stream>>>(
      L1rm, 132, MTOT, 0, Wt1, 132, nullptr, 0, BIG, 128, 0,
      132, T2T, MT, 0, nullptr, 0.f, 0.f, b1, br0, 0);

  // ---- layer 2: 5 slots of 128 rows ----
  {
    const size_t s = (size_t)128 * MT;
    k_mm<128, 128, 0, u16><<<dim3(1, 16, BB), 256, 0, stream>>>(
        Lbuf, NN, NN, (long)NN * NN, T2T, MT, nullptr, 0, BIG, 128, NN,
        NN, T2T + s, MT, NN, nullptr, 1.f, 0.f, nullptr, nullptr, 0);
    for (int k = 2; k < 5; ++k)
      k_mm<128, 128, 0, u16><<<dim3(1, 16, BB), 256, 0, stream>>>(
          Lbuf, NN, NN, (long)NN * NN, T2T + (k - 1) * s, MT, nullptr, 0, BIG, 128, NN,
          NN, T2T + k * s, MT, NN, T2T + (k - 2) * s, 2.f, -1.f, nullptr, nullptr, 0);
  }
  k_actT<<<dim3(512, 10), 256, 0, stream>>>(T2T, L2rm, 640);
  // combine2 -> T3T slot0 (transposed)
  k_mm<128, 128, 1, u16><<<dim3(4, 256, 1), 256, 0, stream>>>(
      L2rm, 640, MTOT, 0, Wt2, 640, nullptr, 0, BIG, 512, 0,
      640, T3T, MT, 0, nullptr, 0.f, 0.f, b2, br1, 0);

  // ---- layer 3: 3 slots of 512 rows ----
  {
    const size_t s = (size_t)512 * MT;
    k_mm<128, 128, 0, u16><<<dim3(4, 16, BB), 256, 0, stream>>>(
        Lbuf, NN, NN, (long)NN * NN, T3T, MT, nullptr, 0, BIG, 512, NN,
        NN, T3T + s, MT, NN, nullptr, 1.f, 0.f, nullptr, nullptr, 0);
    k_mm<128, 128, 0, u16><<<dim3(4, 16, BB), 256, 0, stream>>>(
        Lbuf, NN, NN, (long)NN * NN, T3T + s, MT, nullptr, 0, BIG, 512, NN,
        NN, T3T + 2 * s, MT, NN, T3T, 2.f, -1.f, nullptr, nullptr, 0);
  }
  k_actT<<<dim3(512, 24), 256, 0, stream>>>(T3T, L3rm, 1536);   // L dead -> Lbuf reused
  // combine3 (fc orientation) -> h3rm [M][1024]
  k_mm<128, 128, 1, u16><<<dim3(256, 8, 1), 256, 0, stream>>>(
      Wt3, 1536, 1024, 0, L3rm, 1536, nullptr, 0, BIG, MTOT, 0,
      1536, h3rm, 1024, 0, nullptr, 0.f, 0.f, b3, br2, 1);

  // fc1 -> fc1o [M][512]
  k_mm<128, 128, 1, u16><<<dim3(256, 4, 1), 256, 0, stream>>>(
      Wtf1, 1024, 512, 0, h3rm, 1024, nullptr, 0, BIG, MTOT, 0,
      1024, fc1o, 512, 0, nullptr, 0.f, 0.f, fc1b, br3, 1);
  // fc2: K 2-region [fc1o | L3rm slot0] -> h5 [M][128]
  k_mm<128, 128, 1, u16><<<dim3(256, 1, 1), 256, 0, stream>>>(
      Wtf2, 1024, 128, 0, fc1o, 512, L3rm, 1536, 512, MTOT, 0,
      1024, h5, 128, 0, nullptr, 0.f, 0.f, fc2b, br4, 1);
  // fc3 -> d_out fp32 [M][50]
  k_mm<64, 128, 1, float><<<dim3(256, 1, 1), 256, 0, stream>>>(
      Wtf3, 128, 50, 0, h5, 128, nullptr, 0, BIG, MTOT, 0,
      128, (float*)d_out, 50, 0, nullptr, 0.f, 0.f, fc3b, br5, 1);
}

// Round 6
// 2024.176 us; speedup vs baseline: 2.8830x; 1.1915x over previous
//
#include <hip/hip_runtime.h>

#define BB 16
#define NN 2048
#define FIN 6
#define MTOT (BB*NN)   // 32768

typedef unsigned short u16;
typedef __attribute__((ext_vector_type(8))) short  short8;
typedef __attribute__((ext_vector_type(8))) unsigned short ush8;
typedef __attribute__((ext_vector_type(4))) float  f32x4;

// ---- bf16 helpers ----------------------------------------------------------
__device__ inline float ldf(const u16* p) {
  unsigned u = ((unsigned)*p) << 16; float f; __builtin_memcpy(&f, &u, 4); return f;
}
__device__ inline u16 tobf(float v) {
  unsigned u; __builtin_memcpy(&u, &v, 4);
  u = (u + 0x7FFFu + ((u >> 16) & 1u)) >> 16;   // RNE
  return (u16)u;
}
__device__ inline void stf(u16* p, float v) { *p = tobf(v); }

// ---------------------------------------------------------------------------
// dinv[b,i] = 1/sqrt( sum_j exp(-||x_i-x_j||^2) )
// ---------------------------------------------------------------------------
__global__ __launch_bounds__(256) void k_dinv(const float* __restrict__ x,
                                              float* __restrict__ dinv) {
  __shared__ float xs[NN][FIN];
  __shared__ float sqs[NN];
  const int b = blockIdx.y;
  const float* xb = x + (size_t)b * NN * FIN;
  for (int l = threadIdx.x; l < NN * FIN; l += 256) ((float*)xs)[l] = xb[l];
  __syncthreads();
  for (int j = threadIdx.x; j < NN; j += 256) {
    float s = 0.f;
#pragma unroll
    for (int f = 0; f < FIN; ++f) { float v = xs[j][f]; s = fmaf(v, v, s); }
    sqs[j] = s;
  }
  __syncthreads();
  const int i = blockIdx.x * 256 + threadIdx.x;
  float xi[FIN];
#pragma unroll
  for (int f = 0; f < FIN; ++f) xi[f] = xs[i][f];
  const float sqi = sqs[i];
  float a0 = 0.f, a1 = 0.f, a2 = 0.f, a3 = 0.f;
  for (int j = 0; j < NN; j += 4) {
#pragma unroll
    for (int u = 0; u < 4; ++u) {
      const int jj = j + u;
      float dot = 0.f;
#pragma unroll
      for (int f = 0; f < FIN; ++f) dot = fmaf(xs[jj][f], xi[f], dot);
      const float e = __expf(2.f * dot - sqi - sqs[jj]);
      if (u == 0) a0 += e; else if (u == 1) a1 += e; else if (u == 2) a2 += e; else a3 += e;
    }
  }
  dinv[b * NN + i] = 1.0f / sqrtf((a0 + a1) + (a2 + a3));
}

// ---------------------------------------------------------------------------
// L[b,i,j] = (i==j) - exp(-d2_ij)*dinv_i*dinv_j   (bf16)
// ---------------------------------------------------------------------------
__global__ __launch_bounds__(256) void k_lap(const float* __restrict__ x,
                                             const float* __restrict__ dinv,
                                             u16* __restrict__ Lm) {
  const int b = blockIdx.z;
  const int i0 = blockIdx.y * 32;
  const int j0 = blockIdx.x * 256;
  __shared__ float xi[32][FIN];
  __shared__ float di[32];
  const int t = threadIdx.x;
  const float* xb = x + (size_t)b * NN * FIN;
  if (t < 32 * FIN) ((float*)xi)[t] = xb[i0 * FIN + t];
  if (t >= 224) di[t - 224] = dinv[b * NN + i0 + (t - 224)];
  const int j = j0 + t;
  float xj[FIN];
#pragma unroll
  for (int f = 0; f < FIN; ++f) xj[f] = xb[j * FIN + f];
  float sqj = 0.f;
#pragma unroll
  for (int f = 0; f < FIN; ++f) sqj = fmaf(xj[f], xj[f], sqj);
  const float dj = dinv[b * NN + j];
  __syncthreads();
  u16* Lb = Lm + (size_t)b * NN * NN;
#pragma unroll 4
  for (int ii = 0; ii < 32; ++ii) {
    float sqi = 0.f, dot = 0.f;
#pragma unroll
    for (int f = 0; f < FIN; ++f) {
      const float v = xi[ii][f];
      sqi = fmaf(v, v, sqi);
      dot = fmaf(v, xj[f], dot);
    }
    float val = -__expf(2.f * dot - sqi - sqj) * di[ii] * dj;
    if (i0 + ii == j) val += 1.f;
    stf(&Lb[(size_t)(i0 + ii) * NN + j], val);
  }
}

// ---------------------------------------------------------------------------
// T1T rows [22][Mtot]: row c, col m
// ---------------------------------------------------------------------------
__global__ void k_h0T(const float* __restrict__ x, const int* __restrict__ cat,
                      u16* __restrict__ T1T) {
  const int c = blockIdx.y;
  const int m = blockIdx.x * 256 + threadIdx.x;
  float v;
  if (c < 6) v = x[(size_t)m * 6 + c];
  else v = (cat[m >> 11] == (c - 6)) ? 1.f : 0.f;
  stf(&T1T[(size_t)c * MTOT + m], v);
}

// ---------------------------------------------------------------------------
// weight transpose: in fp32 [R][C] -> out bf16 [C][R]
// ---------------------------------------------------------------------------
__global__ void k_wt(const float* __restrict__ in, u16* __restrict__ out, int R, int C) {
  const int r = blockIdx.x * 256 + threadIdx.x;
  const int c = blockIdx.y;
  if (r < R) stf(&out[(size_t)c * R + r], in[(size_t)r * C + c]);
}

// ---------------------------------------------------------------------------
// activation transpose: in bf16 [F][Mt] -> out bf16 [Mt][F]
// ---------------------------------------------------------------------------
__global__ __launch_bounds__(256) void k_actT(const u16* __restrict__ in,
                                              u16* __restrict__ out, int F) {
  __shared__ u16 t[64][70];
  const int m0 = blockIdx.x * 64;
  const int f0 = blockIdx.y * 64;
  const int tid = threadIdx.x;
#pragma unroll
  for (int v = 0; v < 4; ++v) {
    const int flat = v * 256 + tid;
    const int fr = flat >> 4;
    const int mq = (flat & 15) * 4;
    ushort4 val = {0, 0, 0, 0};
    if (f0 + fr < F) val = *(const ushort4*)&in[(size_t)(f0 + fr) * MTOT + m0 + mq];
    t[fr][mq + 0] = val.x; t[fr][mq + 1] = val.y;
    t[fr][mq + 2] = val.z; t[fr][mq + 3] = val.w;
  }
  __syncthreads();
#pragma unroll
  for (int v = 0; v < 4; ++v) {
    const int flat = v * 256 + tid;
    const int mr = flat >> 4;
    const int fq = (flat & 15) * 4;
    if (f0 + fq >= F) continue;
    u16* dst = &out[(size_t)(m0 + mr) * F + f0 + fq];
    if (f0 + fq + 3 < F) {
      ushort4 o;
      o.x = t[fq + 0][mr]; o.y = t[fq + 1][mr];
      o.z = t[fq + 2][mr]; o.w = t[fq + 3][mr];
      *(ushort4*)dst = o;
    } else {
#pragma unroll
      for (int e = 0; e < 4; ++e)
        if (f0 + fq + e < F) dst[e] = t[fq + e][mr];
    }
  }
}

// ---------------------------------------------------------------------------
// loadTile: global -> regs (R rows x 64 k, two-region K, bounds-checked)
// ---------------------------------------------------------------------------
template <int R>
__device__ inline void loadTile(ush8* dst,
                                const u16* __restrict__ p0, long ld0,
                                const u16* __restrict__ p1, long ld1, int ksplit,
                                int rbase, int rowN, int k0, int K, int tid) {
#pragma unroll
  for (int v = 0; v < R / 32; ++v) {
    const int flat = v * 256 + tid;
    const int r = flat >> 3;
    const int ks = (flat & 7) * 8;
    const int gr = rbase + r;
    const int gk = k0 + ks;
    ush8 tmp;
    if (gr < rowN) {
      const u16* p = nullptr; long ld = 0; int col = 0;
      if (gk + 8 <= ksplit) { p = p0; ld = ld0; col = gk; }
      else if (gk >= ksplit) { p = p1; ld = ld1; col = gk - ksplit; }
      if (p && gk + 8 <= K) {
        const u16* a = p + (size_t)gr * ld + col;
        if (((uintptr_t)a & 15) == 0) {
          tmp = *(const ush8*)a;
        } else {
#pragma unroll
          for (int e = 0; e < 8; ++e) tmp[e] = a[e];
        }
      } else {
#pragma unroll
        for (int e = 0; e < 8; ++e) {
          const int kk = gk + e;
          u16 val = 0;
          if (kk < K) {
            if (kk < ksplit) val = p0[(size_t)gr * ld0 + kk];
            else val = p1[(size_t)gr * ld1 + (kk - ksplit)];
          }
          tmp[e] = val;
        }
      }
    } else {
#pragma unroll
      for (int e = 0; e < 8; ++e) tmp[e] = 0;
    }
    dst[v] = tmp;
  }
}

// writeTile: regs -> swizzled LDS
template <int R>
__device__ inline void writeTile(u16* __restrict__ s, const ush8* src, int tid) {
#pragma unroll
  for (int v = 0; v < R / 32; ++v) {
    const int flat = v * 256 + tid;
    const int r = flat >> 3;
    const int ks = (flat & 7) * 8;
    const int c = ks ^ ((r & 7) << 3);
    *(ush8*)&s[r * 64 + c] = src[v];
  }
}

// ---------------------------------------------------------------------------
// MFMA GEMM: D[i][j] = sum_k P[i][k] * Q[j][k]   (both operands k-fast rows)
// store: Out[jj*ldo + ii]  ([j][i-fast], matches mfma C layout)
// EPI 0: v = alpha*acc + beta*Prev[jj*ldo+ii]        (cheb)
// EPI 1: v = relu(acc + bias[idx] + br[idx])         (idx = i if biasOnI else j)
// Software-pipelined: prefetch tile t+1 into regs while computing tile t.
// ---------------------------------------------------------------------------
template <int BM, int BN, int EPI, typename OT>
__global__ __launch_bounds__(256) void k_mm(
    const u16* __restrict__ P, long ldp, int rowsP, long strideP,
    const u16* __restrict__ Q0, long ldq0,
    const u16* __restrict__ Q1, long ldq1, int ksplit,
    int rowsQ, long strideQ,
    int K,
    OT* __restrict__ Out, long ldo, long strideO,
    const u16* __restrict__ Prev, float alpha, float beta,
    const float* __restrict__ bias, const float* __restrict__ br, int biasOnI) {
  const int b = blockIdx.z;
  const int i0 = blockIdx.y * BM;
  const int j0 = blockIdx.x * BN;
  const u16* Pb = P + (size_t)b * strideP;
  const u16* Qb0 = Q0 + (size_t)b * strideQ;
  const u16* Qb1 = Q1 ? Q1 + (size_t)b * strideQ : nullptr;
  OT* Ob = Out + (size_t)b * strideO;
  const u16* Vb = Prev ? Prev + (size_t)b * strideO : nullptr;

  __shared__ u16 Ps[BM * 64];
  __shared__ u16 Qs[BN * 64];
  const int tid = threadIdx.x;
  const int lane = tid & 63;
  const int w = tid >> 6;
  const int wr = w >> 1, wc = w & 1;
  constexpr int FI = BM / 32;
  constexpr int FJ = BN / 32;
  constexpr int PBIG = 0x40000000;
  f32x4 acc[FI][FJ];
#pragma unroll
  for (int i = 0; i < FI; ++i)
#pragma unroll
    for (int j = 0; j < FJ; ++j) acc[i][j] = (f32x4){0.f, 0.f, 0.f, 0.f};

  auto compute = [&]() {
#pragma unroll
    for (int h = 0; h < 2; ++h) {
      short8 pf[FI], qf[FJ];
#pragma unroll
      for (int i = 0; i < FI; ++i) {
        const int r = wr * (BM / 2) + i * 16 + (lane & 15);
        const int c = (h * 32 + ((lane >> 4) * 8)) ^ ((r & 7) << 3);
        pf[i] = *(const short8*)&Ps[r * 64 + c];
      }
#pragma unroll
      for (int j = 0; j < FJ; ++j) {
        const int r = wc * (BN / 2) + j * 16 + (lane & 15);
        const int c = (h * 32 + ((lane >> 4) * 8)) ^ ((r & 7) << 3);
        qf[j] = *(const short8*)&Qs[r * 64 + c];
      }
#pragma unroll
      for (int i = 0; i < FI; ++i)
#pragma unroll
        for (int j = 0; j < FJ; ++j)
          acc[i][j] = __builtin_amdgcn_mfma_f32_16x16x32_bf16(pf[i], qf[j], acc[i][j], 0, 0, 0);
    }
  };

  const int nk = (K + 63) >> 6;
  ush8 pA[FI], qA[FJ], pB[FI], qB[FJ];
  loadTile<BM>(pA, Pb, ldp, nullptr, 0, PBIG, i0, rowsP, 0, K, tid);
  loadTile<BN>(qA, Qb0, ldq0, Qb1, ldq1, ksplit, j0, rowsQ, 0, K, tid);
  int t = 0;
  while (true) {
    // even phase: prefetch into B, consume A
    if (t + 1 < nk) {
      loadTile<BM>(pB, Pb, ldp, nullptr, 0, PBIG, i0, rowsP, (t + 1) * 64, K, tid);
      loadTile<BN>(qB, Qb0, ldq0, Qb1, ldq1, ksplit, j0, rowsQ, (t + 1) * 64, K, tid);
    }
    writeTile<BM>(Ps, pA, tid);
    writeTile<BN>(Qs, qA, tid);
    __syncthreads();
    compute();
    if (++t >= nk) break;
    __syncthreads();
    // odd phase: prefetch into A, consume B
    if (t + 1 < nk) {
      loadTile<BM>(pA, Pb, ldp, nullptr, 0, PBIG, i0, rowsP, (t + 1) * 64, K, tid);
      loadTile<BN>(qA, Qb0, ldq0, Qb1, ldq1, ksplit, j0, rowsQ, (t + 1) * 64, K, tid);
    }
    writeTile<BM>(Ps, pB, tid);
    writeTile<BN>(Qs, qB, tid);
    __syncthreads();
    compute();
    if (++t >= nk) break;
    __syncthreads();
  }

  const int ibase = i0 + wr * (BM / 2);
  const int jbase = j0 + wc * (BN / 2);
#pragma unroll
  for (int j = 0; j < FJ; ++j) {
    const int jj = jbase + j * 16 + (lane & 15);
    if (jj >= rowsQ) continue;
    float bj = 0.f;
    if (EPI == 1 && !biasOnI) bj = bias[jj] + br[jj];
#pragma unroll
    for (int i = 0; i < FI; ++i) {
      const int ii = ibase + i * 16 + ((lane >> 4) << 2);
      f32x4 a = acc[i][j];
      float v[4];
#pragma unroll
      for (int e = 0; e < 4; ++e) {
        float xv = a[e];
        if (EPI == 0) {
          xv *= alpha;
          if (beta != 0.f) xv = fmaf(beta, ldf(&Vb[(size_t)jj * ldo + ii + e]), xv);
        } else {
          float bb = bj;
          if (biasOnI) bb = (ii + e < rowsP) ? (bias[ii + e] + br[ii + e]) : 0.f;
          xv = fmaxf(xv + bb, 0.f);
        }
        v[e] = xv;
      }
      if constexpr (sizeof(OT) == 2) {
        u16* dst = (u16*)&Ob[(size_t)jj * ldo + ii];
        if (ii + 3 < rowsP) {
          ushort4 o; o.x = tobf(v[0]); o.y = tobf(v[1]); o.z = tobf(v[2]); o.w = tobf(v[3]);
          *(ushort4*)dst = o;
        } else {
#pragma unroll
          for (int e = 0; e < 4; ++e) if (ii + e < rowsP) dst[e] = tobf(v[e]);
        }
      } else {
        float* dst = (float*)&Ob[(size_t)jj * ldo + ii];
#pragma unroll
        for (int e = 0; e < 4; ++e) if (ii + e < rowsP) dst[e] = v[e];
      }
    }
  }
}

// ---------------------------------------------------------------------------
extern "C" void kernel_launch(void* const* d_in, const int* in_sizes, int n_in,
                              void* d_out, int out_size, void* d_ws, size_t ws_size,
                              hipStream_t stream) {
  const float* x    = (const float*)d_in[0];
  const int*   cat  = (const int*)  d_in[1];
  const float* W1   = (const float*)d_in[2];
  const float* b1   = (const float*)d_in[3];
  const float* W2   = (const float*)d_in[4];
  const float* b2   = (const float*)d_in[5];
  const float* W3   = (const float*)d_in[6];
  const float* b3   = (const float*)d_in[7];
  const float* fc1w = (const float*)d_in[8];
  const float* fc1b = (const float*)d_in[9];
  const float* fc2w = (const float*)d_in[10];
  const float* fc2b = (const float*)d_in[11];
  const float* fc3w = (const float*)d_in[12];
  const float* fc3b = (const float*)d_in[13];
  const float* br0  = (const float*)d_in[14];
  const float* br1  = (const float*)d_in[15];
  const float* br2  = (const float*)d_in[16];
  const float* br3  = (const float*)d_in[17];
  const float* br4  = (const float*)d_in[18];
  const float* br5  = (const float*)d_in[19];

  if (ws_size < 240170496ull) return;  // fail loudly

  u16* ws = (u16*)d_ws;
  u16* Wt1  = ws;                    // [128][132]
  u16* Wt2  = Wt1 + 16896;           // [512][640]
  u16* Wt3  = Wt2 + 327680;          // [1024][1536]
  u16* Wtf1 = Wt3 + 1572864;         // [512][1024]
  u16* Wtf2 = Wtf1 + 524288;         // [128][1024]
  u16* Wtf3 = Wtf2 + 131072;         // [50][128]
  float* dinv = (float*)(Wtf3 + 6400);
  u16* Lbuf = ws + 2644736;          // [16][2048][2048] -> later L3rm [M][1536]
  u16* ACT  = Lbuf + 67108864;       // 50,331,648 elems

  u16* T1T   = ACT;                  // [132][M]
  u16* L1rm  = ACT + 4325376;        // [M][132]
  u16* T2T   = ACT;                  // [640][M]
  u16* L2rm  = ACT + 20971520;       // [M][640]
  u16* T3T   = ACT;                  // [1536][M]
  u16* L3rm  = Lbuf;                 // [M][1536]
  u16* h3rm  = ACT;                  // [M][1024]
  u16* fc1o  = ACT + 33554432;       // [M][512]
  u16* h5    = ACT;                  // [M][128]

  const long MT = MTOT;
  const int BIG = 0x40000000;

  // weights -> bf16 transposed
  k_wt<<<dim3(1, 128), 256, 0, stream>>>(W1, Wt1, 132, 128);
  k_wt<<<dim3(3, 512), 256, 0, stream>>>(W2, Wt2, 640, 512);
  k_wt<<<dim3(6, 1024), 256, 0, stream>>>(W3, Wt3, 1536, 1024);
  k_wt<<<dim3(4, 512), 256, 0, stream>>>(fc1w, Wtf1, 1024, 512);
  k_wt<<<dim3(4, 128), 256, 0, stream>>>(fc2w, Wtf2, 1024, 128);
  k_wt<<<dim3(1, 50), 256, 0, stream>>>(fc3w, Wtf3, 128, 50);

  // Laplacian (bf16)
  k_dinv<<<dim3(8, BB), 256, 0, stream>>>(x, dinv);
  k_lap<<<dim3(8, 64, BB), 256, 0, stream>>>(x, dinv, Lbuf);

  // ---- layer 1: 6 slots of 22 rows in T1T ----  (32x32 tiles: 1024 blocks)
  k_h0T<<<dim3(128, 22), 256, 0, stream>>>(x, cat, T1T);
  {
    const size_t s = (size_t)22 * MT;
    k_mm<32, 32, 0, u16><<<dim3(1, 64, BB), 256, 0, stream>>>(
        Lbuf, NN, NN, (long)NN * NN, T1T, MT, nullptr, 0, BIG, 22, NN,
        NN, T1T + s, MT, NN, nullptr, 1.f, 0.f, nullptr, nullptr, 0);
    for (int k = 2; k < 6; ++k)
      k_mm<32, 32, 0, u16><<<dim3(1, 64, BB), 256, 0, stream>>>(
          Lbuf, NN, NN, (long)NN * NN, T1T + (k - 1) * s, MT, nullptr, 0, BIG, 22, NN,
          NN, T1T + k * s, MT, NN, T1T + (k - 2) * s, 2.f, -1.f, nullptr, nullptr, 0);
  }
  k_actT<<<dim3(512, 3), 256, 0, stream>>>(T1T, L1rm, 132);
  // combine1 -> T2T slot0 (transposed)
  k_mm<128, 128, 1, u16><<<dim3(1, 256, 1), 256, 0, stream>>>(
      L1rm, 132, MTOT, 0, Wt1, 132, nullptr, 0, BIG, 128, 0,
      132, T2T, MT, 0, nullptr, 0.f, 0.f, b1, br0, 0);

  // ---- layer 2: 5 slots of 128 rows ----  (64x64 tiles: 1024 blocks)
  {
    const size_t s = (size_t)128 * MT;
    k_mm<64, 64, 0, u16><<<dim3(2, 32, BB), 256, 0, stream>>>(
        Lbuf, NN, NN, (long)NN * NN, T2T, MT, nullptr, 0, BIG, 128, NN,
        NN, T2T + s, MT, NN, nullptr, 1.f, 0.f, nullptr, nullptr, 0);
    for (int k = 2; k < 5; ++k)
      k_mm<64, 64, 0, u16><<<dim3(2, 32, BB), 256, 0, stream>>>(
          Lbuf, NN, NN, (long)NN * NN, T2T + (k - 1) * s, MT, nullptr, 0, BIG, 128, NN,
          NN, T2T + k * s, MT, NN, T2T + (k - 2) * s, 2.f, -1.f, nullptr, nullptr, 0);
  }
  k_actT<<<dim3(512, 10), 256, 0, stream>>>(T2T, L2rm, 640);
  // combine2 -> T3T slot0 (transposed)
  k_mm<128, 128, 1, u16><<<dim3(4, 256, 1), 256, 0, stream>>>(
      L2rm, 640, MTOT, 0, Wt2, 640, nullptr, 0, BIG, 512, 0,
      640, T3T, MT, 0, nullptr, 0.f, 0.f, b2, br1, 0);

  // ---- layer 3: 3 slots of 512 rows ----
  {
    const size_t s = (size_t)512 * MT;
    k_mm<128, 128, 0, u16><<<dim3(4, 16, BB), 256, 0, stream>>>(
        Lbuf, NN, NN, (long)NN * NN, T3T, MT, nullptr, 0, BIG, 512, NN,
        NN, T3T + s, MT, NN, nullptr, 1.f, 0.f, nullptr, nullptr, 0);
    k_mm<128, 128, 0, u16><<<dim3(4, 16, BB), 256, 0, stream>>>(
        Lbuf, NN, NN, (long)NN * NN, T3T + s, MT, nullptr, 0, BIG, 512, NN,
        NN, T3T + 2 * s, MT, NN, T3T, 2.f, -1.f, nullptr, nullptr, 0);
  }
  k_actT<<<dim3(512, 24), 256, 0, stream>>>(T3T, L3rm, 1536);   // L dead -> Lbuf reused
  // combine3 (fc orientation) -> h3rm [M][1024]
  k_mm<128, 128, 1, u16><<<dim3(256, 8, 1), 256, 0, stream>>>(
      Wt3, 1536, 1024, 0, L3rm, 1536, nullptr, 0, BIG, MTOT, 0,
      1536, h3rm, 1024, 0, nullptr, 0.f, 0.f, b3, br2, 1);

  // fc1 -> fc1o [M][512]
  k_mm<128, 128, 1, u16><<<dim3(256, 4, 1), 256, 0, stream>>>(
      Wtf1, 1024, 512, 0, h3rm, 1024, nullptr, 0, BIG, MTOT, 0,
      1024, fc1o, 512, 0, nullptr, 0.f, 0.f, fc1b, br3, 1);
  // fc2: K 2-region [fc1o | L3rm slot0] -> h5 [M][128]  (64x64: 1024 blocks)
  k_mm<64, 64, 1, u16><<<dim3(512, 2, 1), 256, 0, stream>>>(
      Wtf2, 1024, 128, 0, fc1o, 512, L3rm, 1536, 512, MTOT, 0,
      1024, h5, 128, 0, nullptr, 0.f, 0.f, fc2b, br4, 1);
  // fc3 -> d_out fp32 [M][50]
  k_mm<64, 64, 1, float><<<dim3(512, 1, 1), 256, 0, stream>>>(
      Wtf3, 128, 50, 0, h5, 128, nullptr, 0, BIG, MTOT, 0,
      128, (float*)d_out, 50, 0, nullptr, 0.f, 0.f, fc3b, br5, 1);
}

// Round 7
// 1125.421 us; speedup vs baseline: 5.1853x; 1.7986x over previous
//
#include <hip/hip_runtime.h>

#define BB 16
#define NN 2048
#define FIN 6
#define MTOT (BB*NN)   // 32768

typedef unsigned short u16;
typedef __attribute__((ext_vector_type(8))) short  short8;
typedef __attribute__((ext_vector_type(4))) float  f32x4;

// ---- bf16 helpers ----------------------------------------------------------
__device__ inline float ldf(const u16* p) {
  unsigned u = ((unsigned)*p) << 16; float f; __builtin_memcpy(&f, &u, 4); return f;
}
__device__ inline u16 tobf(float v) {
  unsigned u; __builtin_memcpy(&u, &v, 4);
  u = (u + 0x7FFFu + ((u >> 16) & 1u)) >> 16;   // RNE
  return (u16)u;
}
__device__ inline void stf(u16* p, float v) { *p = tobf(v); }

// async global->LDS, 16 bytes per lane (dest = wave-uniform base + lane*16)
__device__ __forceinline__ void gload16(const u16* g, u16* l) {
  __builtin_amdgcn_global_load_lds(
      (const __attribute__((address_space(1))) void*)g,
      (__attribute__((address_space(3))) void*)l, 16, 0, 0);
}

// ---------------------------------------------------------------------------
// partial row-sums of adj: dsum[b,i] += sum_{j in chunk} exp(-||x_i-x_j||^2)
// grid (NN/256, BB, 4); k_rsq then turns dsum into 1/sqrt.
// ---------------------------------------------------------------------------
__global__ __launch_bounds__(256) void k_dpart(const float* __restrict__ x,
                                               float* __restrict__ dsum) {
  __shared__ float xs[512][FIN];
  __shared__ float sqs[512];
  const int b = blockIdx.y;
  const int j0 = blockIdx.z * 512;
  const float* xb = x + (size_t)b * NN * FIN;
  for (int l = threadIdx.x; l < 512 * FIN; l += 256) ((float*)xs)[l] = xb[(size_t)j0 * FIN + l];
  __syncthreads();
  for (int j = threadIdx.x; j < 512; j += 256) {
    float s = 0.f;
#pragma unroll
    for (int f = 0; f < FIN; ++f) { float v = xs[j][f]; s = fmaf(v, v, s); }
    sqs[j] = s;
  }
  __syncthreads();
  const int i = blockIdx.x * 256 + threadIdx.x;
  float xi[FIN];
#pragma unroll
  for (int f = 0; f < FIN; ++f) xi[f] = xb[(size_t)i * FIN + f];
  float sqi = 0.f;
#pragma unroll
  for (int f = 0; f < FIN; ++f) sqi = fmaf(xi[f], xi[f], sqi);
  float a0 = 0.f, a1 = 0.f, a2 = 0.f, a3 = 0.f;
  for (int j = 0; j < 512; j += 4) {
#pragma unroll
    for (int u = 0; u < 4; ++u) {
      const int jj = j + u;
      float dot = 0.f;
#pragma unroll
      for (int f = 0; f < FIN; ++f) dot = fmaf(xs[jj][f], xi[f], dot);
      const float e = __expf(2.f * dot - sqi - sqs[jj]);
      if (u == 0) a0 += e; else if (u == 1) a1 += e; else if (u == 2) a2 += e; else a3 += e;
    }
  }
  atomicAdd(&dsum[b * NN + i], (a0 + a1) + (a2 + a3));
}

__global__ void k_rsq(float* __restrict__ d) {
  const int i = blockIdx.x * 256 + threadIdx.x;
  d[i] = 1.0f / sqrtf(d[i]);
}

// ---------------------------------------------------------------------------
// L[b,i,j] = (i==j) - exp(-d2_ij)*dinv_i*dinv_j   (bf16)
// ---------------------------------------------------------------------------
__global__ __launch_bounds__(256) void k_lap(const float* __restrict__ x,
                                             const float* __restrict__ dinv,
                                             u16* __restrict__ Lm) {
  const int b = blockIdx.z;
  const int i0 = blockIdx.y * 32;
  const int j0 = blockIdx.x * 256;
  __shared__ float xi[32][FIN];
  __shared__ float di[32];
  const int t = threadIdx.x;
  const float* xb = x + (size_t)b * NN * FIN;
  if (t < 32 * FIN) ((float*)xi)[t] = xb[i0 * FIN + t];
  if (t >= 224) di[t - 224] = dinv[b * NN + i0 + (t - 224)];
  const int j = j0 + t;
  float xj[FIN];
#pragma unroll
  for (int f = 0; f < FIN; ++f) xj[f] = xb[j * FIN + f];
  float sqj = 0.f;
#pragma unroll
  for (int f = 0; f < FIN; ++f) sqj = fmaf(xj[f], xj[f], sqj);
  const float dj = dinv[b * NN + j];
  __syncthreads();
  u16* Lb = Lm + (size_t)b * NN * NN;
#pragma unroll 4
  for (int ii = 0; ii < 32; ++ii) {
    float sqi = 0.f, dot = 0.f;
#pragma unroll
    for (int f = 0; f < FIN; ++f) {
      const float v = xi[ii][f];
      sqi = fmaf(v, v, sqi);
      dot = fmaf(v, xj[f], dot);
    }
    float val = -__expf(2.f * dot - sqi - sqj) * di[ii] * dj;
    if (i0 + ii == j) val += 1.f;
    stf(&Lb[(size_t)(i0 + ii) * NN + j], val);
  }
}

// ---------------------------------------------------------------------------
__global__ void k_h0T(const float* __restrict__ x, const int* __restrict__ cat,
                      u16* __restrict__ T1T) {
  const int c = blockIdx.y;
  const int m = blockIdx.x * 256 + threadIdx.x;
  float v;
  if (c < 6) v = x[(size_t)m * 6 + c];
  else v = (cat[m >> 11] == (c - 6)) ? 1.f : 0.f;
  stf(&T1T[(size_t)c * MTOT + m], v);
}

// weight transpose: fp32 [R][C] -> bf16 [C][ldo] (cols >= R zero-padded by memset)
__global__ void k_wt(const float* __restrict__ in, u16* __restrict__ out,
                     int R, int C, int ldo) {
  const int r = blockIdx.x * 256 + threadIdx.x;
  const int c = blockIdx.y;
  if (r < R) stf(&out[(size_t)c * ldo + r], in[(size_t)r * C + c]);
}

// activation transpose: bf16 [F][Mt] -> bf16 [Mt][ldo]
__global__ __launch_bounds__(256) void k_actT(const u16* __restrict__ in,
                                              u16* __restrict__ out, int F, int ldo) {
  __shared__ u16 t[64][70];
  const int m0 = blockIdx.x * 64;
  const int f0 = blockIdx.y * 64;
  const int tid = threadIdx.x;
#pragma unroll
  for (int v = 0; v < 4; ++v) {
    const int flat = v * 256 + tid;
    const int fr = flat >> 4;
    const int mq = (flat & 15) * 4;
    ushort4 val = {0, 0, 0, 0};
    if (f0 + fr < F) val = *(const ushort4*)&in[(size_t)(f0 + fr) * MTOT + m0 + mq];
    t[fr][mq + 0] = val.x; t[fr][mq + 1] = val.y;
    t[fr][mq + 2] = val.z; t[fr][mq + 3] = val.w;
  }
  __syncthreads();
#pragma unroll
  for (int v = 0; v < 4; ++v) {
    const int flat = v * 256 + tid;
    const int mr = flat >> 4;
    const int fq = (flat & 15) * 4;
    if (f0 + fq >= F) continue;
    u16* dst = &out[(size_t)(m0 + mr) * ldo + f0 + fq];
    if (f0 + fq + 3 < F) {
      ushort4 o;
      o.x = t[fq + 0][mr]; o.y = t[fq + 1][mr];
      o.z = t[fq + 2][mr]; o.w = t[fq + 3][mr];
      *(ushort4*)dst = o;
    } else {
#pragma unroll
      for (int e = 0; e < 4; ++e)
        if (f0 + fq + e < F) dst[e] = t[fq + e][mr];
    }
  }
}

// ---------------------------------------------------------------------------
// MFMA GEMM via global_load_lds: D[i][j] = sum_k P[i][k]*Q[j][k]
// Requires: K % 64 == 0, row leading dims % 8 == 0 (16B-aligned rows).
// LDS image is XOR-swizzled by pre-swizzling the per-lane SOURCE address:
//   lane l of a 1024B chunk (8 rows) loads k-group ((l&7)^(l>>3))*8.
// Out[jj*ldo+ii] ([j][i-fast], mfma C layout). EPI 0: alpha*acc+beta*Prev;
// EPI 1: relu(acc+bias+br) (bias idx = i if biasOnI else j).
// TWOQ: K-tiles t<ksplitT from Q0, else from Q1.
// ---------------------------------------------------------------------------
template <int BM, int BN, int EPI, bool TWOQ, typename OT>
__global__ __launch_bounds__(256) void k_mmL(
    const u16* __restrict__ P, long ldp, int rowsP, long strideP,
    const u16* __restrict__ Q0, long ldq0,
    const u16* __restrict__ Q1, long ldq1, int ksplitT,
    int rowsQ, long strideQ, int K,
    OT* __restrict__ Out, long ldo, long strideO,
    const u16* __restrict__ Prev, float alpha, float beta,
    const float* __restrict__ bias, const float* __restrict__ br, int biasOnI) {
  const int b = blockIdx.z;
  const int i0 = blockIdx.y * BM;
  const int j0 = blockIdx.x * BN;
  const u16* Pb = P + (size_t)b * strideP;
  const u16* Qb0 = Q0 + (size_t)b * strideQ;
  OT* Ob = Out + (size_t)b * strideO;
  const u16* Vb = Prev ? Prev + (size_t)b * strideO : nullptr;

  __shared__ __align__(16) u16 Ps[BM * 64];
  __shared__ __align__(16) u16 Qs[BN * 64];
  const int tid = threadIdx.x;
  const int lane = tid & 63;
  const int w = tid >> 6;
  const int wr = w >> 1, wc = w & 1;
  constexpr int FI = BM / 32;
  constexpr int FJ = BN / 32;
  constexpr int VP = BM / 32;   // P chunks per wave (BM/8 chunks / 4 waves)
  constexpr int VQ = BN / 32;
  const int rl = lane >> 3;                    // row within 8-row chunk
  const int kb = (((lane & 7) ^ rl) << 3);     // pre-swizzled k-group (elements)

  const u16* prow[VP];
  bool pok[VP];
#pragma unroll
  for (int v = 0; v < VP; ++v) {
    const int c = w + v * 4;
    const int gr = i0 + c * 8 + rl;
    pok[v] = gr < rowsP;
    prow[v] = Pb + (size_t)gr * ldp + kb;
  }
  const u16* qrow[VQ];
  const u16* qrow1[TWOQ ? VQ : 1];
  bool qok[VQ];
#pragma unroll
  for (int v = 0; v < VQ; ++v) {
    const int c = w + v * 4;
    const int gr = j0 + c * 8 + rl;
    qok[v] = gr < rowsQ;
    qrow[v] = Qb0 + (size_t)gr * ldq0 + kb;
    if (TWOQ) qrow1[v] = Q1 + (size_t)b * strideQ + (size_t)gr * ldq1 + kb;
  }

  f32x4 acc[FI][FJ];
#pragma unroll
  for (int i = 0; i < FI; ++i)
#pragma unroll
    for (int j = 0; j < FJ; ++j) acc[i][j] = (f32x4){0.f, 0.f, 0.f, 0.f};

  const int nt = K >> 6;
  for (int t = 0; t < nt; ++t) {
#pragma unroll
    for (int v = 0; v < VP; ++v)
      if (pok[v]) gload16(prow[v] + t * 64, &Ps[(w + v * 4) * 512]);
    if (TWOQ) {
      const bool r1 = (t >= ksplitT);
      const int tq = r1 ? (t - ksplitT) : t;
#pragma unroll
      for (int v = 0; v < VQ; ++v)
        if (qok[v]) gload16((r1 ? qrow1[v] : qrow[v]) + tq * 64, &Qs[(w + v * 4) * 512]);
    } else {
#pragma unroll
      for (int v = 0; v < VQ; ++v)
        if (qok[v]) gload16(qrow[v] + t * 64, &Qs[(w + v * 4) * 512]);
    }
    __syncthreads();   // drains vmcnt -> LDS ready
#pragma unroll
    for (int h = 0; h < 2; ++h) {
      short8 pf[FI], qf[FJ];
#pragma unroll
      for (int i = 0; i < FI; ++i) {
        const int r = wr * (BM / 2) + i * 16 + (lane & 15);
        const int c = (h * 32 + ((lane >> 4) * 8)) ^ ((r & 7) << 3);
        pf[i] = *(const short8*)&Ps[r * 64 + c];
      }
#pragma unroll
      for (int j = 0; j < FJ; ++j) {
        const int r = wc * (BN / 2) + j * 16 + (lane & 15);
        const int c = (h * 32 + ((lane >> 4) * 8)) ^ ((r & 7) << 3);
        qf[j] = *(const short8*)&Qs[r * 64 + c];
      }
#pragma unroll
      for (int i = 0; i < FI; ++i)
#pragma unroll
        for (int j = 0; j < FJ; ++j)
          acc[i][j] = __builtin_amdgcn_mfma_f32_16x16x32_bf16(pf[i], qf[j], acc[i][j], 0, 0, 0);
    }
    __syncthreads();
  }

  const int ibase = i0 + wr * (BM / 2);
  const int jbase = j0 + wc * (BN / 2);
#pragma unroll
  for (int j = 0; j < FJ; ++j) {
    const int jj = jbase + j * 16 + (lane & 15);
    if (jj >= rowsQ) continue;
    float bj = 0.f;
    if (EPI == 1 && !biasOnI) bj = bias[jj] + br[jj];
#pragma unroll
    for (int i = 0; i < FI; ++i) {
      const int ii = ibase + i * 16 + ((lane >> 4) << 2);
      f32x4 a = acc[i][j];
      float v[4];
#pragma unroll
      for (int e = 0; e < 4; ++e) {
        float xv = a[e];
        if (EPI == 0) {
          xv *= alpha;
          if (beta != 0.f) xv = fmaf(beta, ldf(&Vb[(size_t)jj * ldo + ii + e]), xv);
        } else {
          float bb = bj;
          if (biasOnI) bb = (ii + e < rowsP) ? (bias[ii + e] + br[ii + e]) : 0.f;
          xv = fmaxf(xv + bb, 0.f);
        }
        v[e] = xv;
      }
      if constexpr (sizeof(OT) == 2) {
        u16* dst = (u16*)&Ob[(size_t)jj * ldo + ii];
        if (ii + 3 < rowsP) {
          ushort4 o; o.x = tobf(v[0]); o.y = tobf(v[1]); o.z = tobf(v[2]); o.w = tobf(v[3]);
          *(ushort4*)dst = o;
        } else {
#pragma unroll
          for (int e = 0; e < 4; ++e) if (ii + e < rowsP) dst[e] = tobf(v[e]);
        }
      } else {
        float* dst = (float*)&Ob[(size_t)jj * ldo + ii];
#pragma unroll
        for (int e = 0; e < 4; ++e) if (ii + e < rowsP) dst[e] = v[e];
      }
    }
  }
}

// ---------------------------------------------------------------------------
extern "C" void kernel_launch(void* const* d_in, const int* in_sizes, int n_in,
                              void* d_out, int out_size, void* d_ws, size_t ws_size,
                              hipStream_t stream) {
  const float* x    = (const float*)d_in[0];
  const int*   cat  = (const int*)  d_in[1];
  const float* W1   = (const float*)d_in[2];
  const float* b1   = (const float*)d_in[3];
  const float* W2   = (const float*)d_in[4];
  const float* b2   = (const float*)d_in[5];
  const float* W3   = (const float*)d_in[6];
  const float* b3   = (const float*)d_in[7];
  const float* fc1w = (const float*)d_in[8];
  const float* fc1b = (const float*)d_in[9];
  const float* fc2w = (const float*)d_in[10];
  const float* fc2b = (const float*)d_in[11];
  const float* fc3w = (const float*)d_in[12];
  const float* fc3b = (const float*)d_in[13];
  const float* br0  = (const float*)d_in[14];
  const float* br1  = (const float*)d_in[15];
  const float* br2  = (const float*)d_in[16];
  const float* br3  = (const float*)d_in[17];
  const float* br4  = (const float*)d_in[18];
  const float* br5  = (const float*)d_in[19];

  if (ws_size < 240054784ull) return;  // fail loudly

  u16* ws = (u16*)d_ws;
  u16* Wt1p = ws;                    // [128][192]  (K padded 132->192, zero tail)
  u16* Wt2  = Wt1p + 24576;          // [512][640]
  u16* Wt3  = Wt2 + 327680;          // [1024][1536]
  u16* Wtf1 = Wt3 + 1572864;         // [512][1024]
  u16* Wtf2 = Wtf1 + 524288;         // [128][1024]
  u16* Wtf3 = Wtf2 + 131072;         // [50][128]
  u16* Lbuf = ws + 2586880;          // [16][2048][2048] -> later L3rm [M][1536]
  u16* ACT  = Lbuf + 67108864;       // 50,331,648 elems

  float* dinv = (float*)ACT;         // dead before T1T written
  u16* T1T   = ACT;                  // [132][M]
  u16* L1rm  = ACT + 4325376;        // [M][192] (cols 132..191 zero)
  u16* T2T   = ACT;                  // [640][M]
  u16* L2rm  = ACT + 20971520;       // [M][640]
  u16* T3T   = ACT;                  // [1536][M]
  u16* L3rm  = Lbuf;                 // [M][1536]
  u16* h3rm  = ACT;                  // [M][1024]
  u16* fc1o  = ACT + 33554432;       // [M][512]
  u16* h5    = ACT;                  // [M][128]

  const long MT = MTOT;
  const int BIG = 1 << 28;

  // zero-init: dinv accumulator, padded W1, padded L1rm
  hipMemsetAsync(dinv, 0, (size_t)MTOT * 4, stream);
  hipMemsetAsync(Wt1p, 0, 24576 * 2, stream);
  hipMemsetAsync(L1rm, 0, (size_t)MTOT * 192 * 2, stream);

  // weights -> bf16 transposed
  k_wt<<<dim3(1, 128), 256, 0, stream>>>(W1, Wt1p, 132, 128, 192);
  k_wt<<<dim3(3, 512), 256, 0, stream>>>(W2, Wt2, 640, 512, 640);
  k_wt<<<dim3(6, 1024), 256, 0, stream>>>(W3, Wt3, 1536, 1024, 1536);
  k_wt<<<dim3(4, 512), 256, 0, stream>>>(fc1w, Wtf1, 1024, 512, 1024);
  k_wt<<<dim3(4, 128), 256, 0, stream>>>(fc2w, Wtf2, 1024, 128, 1024);
  k_wt<<<dim3(1, 50), 256, 0, stream>>>(fc3w, Wtf3, 128, 50, 128);

  // Laplacian (bf16)
  k_dpart<<<dim3(8, BB, 4), 256, 0, stream>>>(x, dinv);
  k_rsq<<<dim3(MTOT / 256), 256, 0, stream>>>(dinv);
  k_lap<<<dim3(8, 64, BB), 256, 0, stream>>>(x, dinv, Lbuf);

  // ---- layer 1: 6 slots of 22 rows in T1T ----
  k_h0T<<<dim3(128, 22), 256, 0, stream>>>(x, cat, T1T);
  {
    const size_t s = (size_t)22 * MT;
    k_mmL<64, 32, 0, false, u16><<<dim3(1, 32, BB), 256, 0, stream>>>(
        Lbuf, NN, NN, (long)NN * NN, T1T, MT, nullptr, 0, BIG, 22, NN,
        NN, T1T + s, MT, NN, nullptr, 1.f, 0.f, nullptr, nullptr, 0);
    for (int k = 2; k < 6; ++k)
      k_mmL<64, 32, 0, false, u16><<<dim3(1, 32, BB), 256, 0, stream>>>(
          Lbuf, NN, NN, (long)NN * NN, T1T + (k - 1) * s, MT, nullptr, 0, BIG, 22, NN,
          NN, T1T + k * s, MT, NN, T1T + (k - 2) * s, 2.f, -1.f, nullptr, nullptr, 0);
  }
  k_actT<<<dim3(512, 3), 256, 0, stream>>>(T1T, L1rm, 132, 192);
  // combine1 (K padded to 192) -> T2T slot0 (transposed)
  k_mmL<128, 128, 1, false, u16><<<dim3(1, 256, 1), 256, 0, stream>>>(
      L1rm, 192, MTOT, 0, Wt1p, 192, nullptr, 0, BIG, 128, 0,
      192, T2T, MT, 0, nullptr, 0.f, 0.f, b1, br0, 0);

  // ---- layer 2: 5 slots of 128 rows ----
  {
    const size_t s = (size_t)128 * MT;
    k_mmL<64, 128, 0, false, u16><<<dim3(1, 32, BB), 256, 0, stream>>>(
        Lbuf, NN, NN, (long)NN * NN, T2T, MT, nullptr, 0, BIG, 128, NN,
        NN, T2T + s, MT, NN, nullptr, 1.f, 0.f, nullptr, nullptr, 0);
    for (int k = 2; k < 5; ++k)
      k_mmL<64, 128, 0, false, u16><<<dim3(1, 32, BB), 256, 0, stream>>>(
          Lbuf, NN, NN, (long)NN * NN, T2T + (k - 1) * s, MT, nullptr, 0, BIG, 128, NN,
          NN, T2T + k * s, MT, NN, T2T + (k - 2) * s, 2.f, -1.f, nullptr, nullptr, 0);
  }
  k_actT<<<dim3(512, 10), 256, 0, stream>>>(T2T, L2rm, 640, 640);
  // combine2 -> T3T slot0 (transposed)
  k_mmL<128, 128, 1, false, u16><<<dim3(4, 256, 1), 256, 0, stream>>>(
      L2rm, 640, MTOT, 0, Wt2, 640, nullptr, 0, BIG, 512, 0,
      640, T3T, MT, 0, nullptr, 0.f, 0.f, b2, br1, 0);

  // ---- layer 3: 3 slots of 512 rows ----
  {
    const size_t s = (size_t)512 * MT;
    k_mmL<128, 128, 0, false, u16><<<dim3(4, 16, BB), 256, 0, stream>>>(
        Lbuf, NN, NN, (long)NN * NN, T3T, MT, nullptr, 0, BIG, 512, NN,
        NN, T3T + s, MT, NN, nullptr, 1.f, 0.f, nullptr, nullptr, 0);
    k_mmL<128, 128, 0, false, u16><<<dim3(4, 16, BB), 256, 0, stream>>>(
        Lbuf, NN, NN, (long)NN * NN, T3T + s, MT, nullptr, 0, BIG, 512, NN,
        NN, T3T + 2 * s, MT, NN, T3T, 2.f, -1.f, nullptr, nullptr, 0);
  }
  k_actT<<<dim3(512, 24), 256, 0, stream>>>(T3T, L3rm, 1536, 1536);  // L dead -> Lbuf reused
  // combine3 (fc orientation) -> h3rm [M][1024]
  k_mmL<128, 128, 1, false, u16><<<dim3(256, 8, 1), 256, 0, stream>>>(
      Wt3, 1536, 1024, 0, L3rm, 1536, nullptr, 0, BIG, MTOT, 0,
      1536, h3rm, 1024, 0, nullptr, 0.f, 0.f, b3, br2, 1);

  // fc1 -> fc1o [M][512]
  k_mmL<128, 128, 1, false, u16><<<dim3(256, 4, 1), 256, 0, stream>>>(
      Wtf1, 1024, 512, 0, h3rm, 1024, nullptr, 0, BIG, MTOT, 0,
      1024, fc1o, 512, 0, nullptr, 0.f, 0.f, fc1b, br3, 1);
  // fc2: K 2-region [fc1o | L3rm slot0] -> h5 [M][128]
  k_mmL<64, 128, 1, true, u16><<<dim3(256, 2, 1), 256, 0, stream>>>(
      Wtf2, 1024, 128, 0, fc1o, 512, L3rm, 1536, 8, MTOT, 0,
      1024, h5, 128, 0, nullptr, 0.f, 0.f, fc2b, br4, 1);
  // fc3 -> d_out fp32 [M][50]
  k_mmL<64, 128, 1, false, float><<<dim3(256, 1, 1), 256, 0, stream>>>(
      Wtf3, 128, 50, 0, h5, 128, nullptr, 0, BIG, MTOT, 0,
      128, (float*)d_out, 50, 0, nullptr, 0.f, 0.f, fc3b, br5, 1);
}